// Round 1
// baseline (103.265 us; speedup 1.0000x reference)
//
#include <hip/hip_runtime.h>
#include <math.h>

// AFM forward, round 6: r5 + serial-overhead removal.
//  - parallel closed-form pair LUT (was: 64-iter serial loop in 64 lanes)
//  - float4 W1/b1/w2 fragment staging (was: 64 scalar loads/thread)
//  - running per-wave softmax max fused into pass 1 (max sweep + barrier deleted)
//  - wave-parallel deep-MLP tail with ping-pong buffers (3 barriers, 4-deep
//    FMA chains; was ~7 barriers, 64-deep serial chains in <=32 lanes)

#define BB 512
#define FF 64
#define STR 68                // halves per row: 136B, 34 dwords
#define NPAIRS 2080
#define THREADS 512
#define NIT2 65               // 130 16-pair tiles, 2 per iteration
#define NEG_BIG -3.402823466e38f

typedef _Float16 half8 __attribute__((ext_vector_type(8)));
typedef _Float16 half4 __attribute__((ext_vector_type(4)));
typedef float f32x4 __attribute__((ext_vector_type(4)));

// 16B row-fragment load from an 8B-aligned row: two ds_read_b64.
__device__ __forceinline__ half8 ld8(const _Float16* p) {
    half8 v;
    *(half4*)&v       = *(const half4*)p;
    *((half4*)&v + 1) = *(const half4*)(p + 4);
    return v;
}

__global__ __launch_bounds__(THREADS, 4) void afm_r6_kernel(
    const float* __restrict__ x,     // [512,64]
    const float* __restrict__ Ww,    // [1,64]
    const float* __restrict__ bw,    // [1]
    const float* __restrict__ cross, // [64,64]
    const float* __restrict__ W1,    // [64,64]
    const float* __restrict__ b1,    // [64]
    const float* __restrict__ w2,    // [64]
    const float* __restrict__ Wd1,   // [32,64]
    const float* __restrict__ bd1,   // [32]
    const float* __restrict__ Wd2,   // [21,32]
    const float* __restrict__ bd2,   // [21]
    const float* __restrict__ Wd3,   // [16,21]
    const float* __restrict__ bd3,   // [16]
    const float* __restrict__ Wo,    // [1,16]
    const float* __restrict__ bo,    // [1]
    float* __restrict__ out)         // [512]
{
    __shared__ __align__(16) _Float16 ah_s [FF * STR];  // a[i][k] f16
    __shared__ __align__(16) _Float16 aht_s[FF * STR];  // a^T[k][i]
    __shared__ __align__(16) _Float16 M_s  [FF * STR];  // e-matrix (upper-tri)
    __shared__ float s_s[NPAIRS];
    __shared__ unsigned short lut_s[NPAIRS];
    __shared__ float x_sh[FF];
    __shared__ float part_s[4][FF];
    __shared__ float mlp_s[FF];
    __shared__ float red_s[16];

    const int tid  = threadIdx.x;
    const int lane = tid & 63;
    const int wave = tid >> 6;
    const int b    = blockIdx.x;
    const int m    = lane & 15;
    const int q    = lane >> 4;

    // ---- stage x ----
    if (tid < FF) x_sh[tid] = x[b * FF + tid];
    __syncthreads();

    // ---- ah/aht (f16), M zero, parallel pair LUT (valid bit 15) ----
    for (int idx = tid; idx < FF * FF; idx += THREADS) {
        const int i = idx >> 6, k = idx & 63;
        const _Float16 v = (_Float16)(x_sh[i] * cross[idx]);
        ah_s[i * STR + k]  = v;
        aht_s[k * STR + i] = v;
    }
    for (int idx = tid; idx < (FF * STR) / 2; idx += THREADS)
        ((int*)M_s)[idx] = 0;
    // closed-form row index: base(i) = i*(129-i)/2; i = floor((129-sqrt(129^2-8p))/2)
    for (int p = tid; p < NPAIRS; p += THREADS) {
        int i = (int)floorf((129.0f - sqrtf(16641.0f - 8.0f * (float)p)) * 0.5f);
        int base = (i * (129 - i)) >> 1;
        if (p < base) { --i; base = (i * (129 - i)) >> 1; }
        else { const int nb = ((i + 1) * (128 - i)) >> 1; if (p >= nb) { ++i; base = nb; } }
        const int j = i + (p - base);
        const int valid = ((x_sh[i] != 0.f) && (x_sh[j] != 0.f)) ? 0x8000 : 0;
        lut_s[p] = (unsigned short)((i << 8) | j | valid);
    }

    // ---- A-fragments (W1->f16) from global, float4 loads; b1/w2 resident ----
    half8 afr[4][2];
    #pragma unroll
    for (int mt = 0; mt < 4; ++mt)
        #pragma unroll
        for (int kt = 0; kt < 2; ++kt) {
            const float* wr = W1 + (mt * 16 + m) * FF + kt * 32 + q * 8;
            const f32x4 w0 = *(const f32x4*)wr;
            const f32x4 w1 = *(const f32x4*)(wr + 4);
            half8 h;
            #pragma unroll
            for (int jj = 0; jj < 4; ++jj) {
                h[jj]     = (_Float16)w0[jj];
                h[4 + jj] = (_Float16)w1[jj];
            }
            afr[mt][kt] = h;
        }
    float b1r[16], w2r[16];
    #pragma unroll
    for (int mt = 0; mt < 4; ++mt) {
        const f32x4 bb = *(const f32x4*)(b1 + mt * 16 + q * 4);
        const f32x4 ww = *(const f32x4*)(w2 + mt * 16 + q * 4);
        #pragma unroll
        for (int r = 0; r < 4; ++r) {
            b1r[mt * 4 + r] = bb[r];
            w2r[mt * 4 + r] = ww[r];
        }
    }
    __syncthreads();

    // ---- pass 1: scores + running per-wave max, 2 tiles (32 pairs)/iter ----
    float wave_mx = 0.0f;   // softmax max is seeded with the 0-logit term
    for (int it = wave; it < NIT2; it += 8) {
        const int p0 = it * 32;
        const int ijA = lut_s[p0 + m];
        const int ijB = lut_s[p0 + 16 + m];
        const int iA = (ijA >> 8) & 63, jA = ijA & 63;
        const int iB = (ijB >> 8) & 63, jB = ijB & 63;
        const half8 bA0 = ld8(&ah_s[iA * STR + q * 8])      * ld8(&ah_s[jA * STR + q * 8]);
        const half8 bA1 = ld8(&ah_s[iA * STR + 32 + q * 8]) * ld8(&ah_s[jA * STR + 32 + q * 8]);
        const half8 bB0 = ld8(&ah_s[iB * STR + q * 8])      * ld8(&ah_s[jB * STR + q * 8]);
        const half8 bB1 = ld8(&ah_s[iB * STR + 32 + q * 8]) * ld8(&ah_s[jB * STR + 32 + q * 8]);
        float spA = 0.f, spB = 0.f;
        #pragma unroll
        for (int mt = 0; mt < 4; ++mt) {
            f32x4 aA, aB;
            #pragma unroll
            for (int r = 0; r < 4; ++r) { aA[r] = b1r[mt * 4 + r]; aB[r] = b1r[mt * 4 + r]; }
            aA = __builtin_amdgcn_mfma_f32_16x16x32_f16(afr[mt][0], bA0, aA, 0, 0, 0);
            aB = __builtin_amdgcn_mfma_f32_16x16x32_f16(afr[mt][0], bB0, aB, 0, 0, 0);
            aA = __builtin_amdgcn_mfma_f32_16x16x32_f16(afr[mt][1], bA1, aA, 0, 0, 0);
            aB = __builtin_amdgcn_mfma_f32_16x16x32_f16(afr[mt][1], bB1, aB, 0, 0, 0);
            #pragma unroll
            for (int r = 0; r < 4; ++r) {
                spA = fmaf(w2r[mt * 4 + r], fmaxf(aA[r], 0.f), spA);
                spB = fmaf(w2r[mt * 4 + r], fmaxf(aB[r], 0.f), spB);
            }
        }
        spA += __shfl_xor(spA, 16, 64);
        spA += __shfl_xor(spA, 32, 64);
        spB += __shfl_xor(spB, 16, 64);
        spB += __shfl_xor(spB, 32, 64);
        // running max over valid pairs (all lanes hold full sums; period-16 in m)
        wave_mx = fmaxf(wave_mx, (ijA & 0x8000) ? spA : 0.f);
        wave_mx = fmaxf(wave_mx, (ijB & 0x8000) ? spB : 0.f);
        if (lane < 16) {
            s_s[p0 + lane]      = spA;   // raw score; validity applied in exp sweep
            s_s[p0 + 16 + lane] = spB;
        }
    }
    wave_mx = fmaxf(wave_mx, __shfl_xor(wave_mx, 1, 64));
    wave_mx = fmaxf(wave_mx, __shfl_xor(wave_mx, 2, 64));
    wave_mx = fmaxf(wave_mx, __shfl_xor(wave_mx, 4, 64));
    wave_mx = fmaxf(wave_mx, __shfl_xor(wave_mx, 8, 64));
    if (lane == 0) red_s[wave] = wave_mx;
    __syncthreads();

    float mval = red_s[0];
    #pragma unroll
    for (int w = 1; w < 8; ++w) mval = fmaxf(mval, red_s[w]);

    // ---- fused: e = exp(s-m) (0 if invalid), M[i][j] = e, sum e ----
    float sum = 0.f;
    for (int p = tid; p < NPAIRS; p += THREADS) {
        const int ij = lut_s[p];
        const float e = (ij & 0x8000) ? __expf(s_s[p] - mval) : 0.f;
        sum += e;
        M_s[((ij >> 8) & 63) * STR + (ij & 63)] = (_Float16)e;
    }
    #pragma unroll
    for (int off = 32; off > 0; off >>= 1)
        sum += __shfl_xor(sum, off, 64);
    if (lane == 0) red_s[8 + wave] = sum;
    __syncthreads();
    float denom = __expf(-mval);
    #pragma unroll
    for (int w = 0; w < 8; ++w) denom += red_s[8 + w];

    // ---- pass 2 as MFMA: g = M @ ah; tmp[k] = sum_i ah[i][k]*g[i][k] ----
    {
        const int t0 = wave * 2;
        #pragma unroll
        for (int t = t0; t < t0 + 2; ++t) {
            const int i0 = (t >> 2) * 16, k0 = (t & 3) * 16;
            const half8 a0  = ld8(&M_s[(i0 + m) * STR + q * 8]);
            const half8 a1  = ld8(&M_s[(i0 + m) * STR + 32 + q * 8]);
            const half8 bb0 = ld8(&aht_s[(k0 + m) * STR + q * 8]);
            const half8 bb1 = ld8(&aht_s[(k0 + m) * STR + 32 + q * 8]);
            f32x4 g = {0.f, 0.f, 0.f, 0.f};
            g = __builtin_amdgcn_mfma_f32_16x16x32_f16(a0, bb0, g, 0, 0, 0);
            g = __builtin_amdgcn_mfma_f32_16x16x32_f16(a1, bb1, g, 0, 0, 0);
            const half4 ap = *(const half4*)&aht_s[(k0 + m) * STR + i0 + q * 4];
            float s4 = (float)ap[0] * g[0] + (float)ap[1] * g[1]
                     + (float)ap[2] * g[2] + (float)ap[3] * g[3];
            s4 += __shfl_xor(s4, 16, 64);
            s4 += __shfl_xor(s4, 32, 64);
            if (lane < 16) part_s[i0 >> 4][k0 + lane] = s4;
        }
    }
    __syncthreads();
    if (tid < FF)
        mlp_s[tid] = (part_s[0][tid] + part_s[1][tid] +
                      part_s[2][tid] + part_s[3][tid]) / denom;
    __syncthreads();

    // ---- deep MLP, wave-parallel with ping-pong buffers ----
    float* tmp2 = part_s[0];   // reuse; part_s fully consumed above

    // stage 1: 64 -> 32.  out = tid>>4, 16 lanes/out, 4 FMAs + 4-shfl tree.
    {
        const int outi = tid >> 4, kp = tid & 15;
        float a = 0.f;
        #pragma unroll
        for (int t = 0; t < 4; ++t)
            a = fmaf(Wd1[outi * 64 + kp + t * 16], mlp_s[kp + t * 16], a);
        a += __shfl_xor(a, 1, 64);
        a += __shfl_xor(a, 2, 64);
        a += __shfl_xor(a, 4, 64);
        a += __shfl_xor(a, 8, 64);
        if (kp == 0) tmp2[outi] = fmaxf(a + bd1[outi], 0.f);
    }
    __syncthreads();

    // stage 2: 32 -> 21.  out = tid>>3 (<21), 8 lanes/out.
    if (tid < 21 * 8) {
        const int outi = tid >> 3, kp = tid & 7;
        float a = 0.f;
        #pragma unroll
        for (int t = 0; t < 4; ++t)
            a = fmaf(Wd2[outi * 32 + kp + t * 8], tmp2[kp + t * 8], a);
        a += __shfl_xor(a, 1, 64);
        a += __shfl_xor(a, 2, 64);
        a += __shfl_xor(a, 4, 64);
        if (kp == 0) mlp_s[outi] = fmaxf(a + bd2[outi], 0.f);
    }
    __syncthreads();

    // stage 3: 21 -> 16.  out = tid>>3 (<16), 8 lanes/out, k = kp,kp+8,kp+16.
    if (tid < 16 * 8) {
        const int outi = tid >> 3, kp = tid & 7;
        float a = Wd3[outi * 21 + kp] * mlp_s[kp];
        a = fmaf(Wd3[outi * 21 + kp + 8], mlp_s[kp + 8], a);
        if (kp < 5) a = fmaf(Wd3[outi * 21 + kp + 16], mlp_s[kp + 16], a);
        a += __shfl_xor(a, 1, 64);
        a += __shfl_xor(a, 2, 64);
        a += __shfl_xor(a, 4, 64);
        if (kp == 0) tmp2[outi] = fmaxf(a + bd3[outi], 0.f);
    }
    __syncthreads();

    // stage 4: wide linear (64) + out head (16) in one wave-reduce.
    if (wave == 0) {
        float v = Ww[lane] * x_sh[lane];
        if (lane < 16) v = fmaf(Wo[lane], tmp2[lane], v);
        #pragma unroll
        for (int off = 32; off > 0; off >>= 1)
            v += __shfl_xor(v, off, 64);
        if (lane == 0) {
            const float z = v + bw[0] + bo[0];
            out[b] = 1.f / (1.f + __expf(-z));
        }
    }
}

extern "C" void kernel_launch(void* const* d_in, const int* in_sizes, int n_in,
                              void* d_out, int out_size, void* d_ws, size_t ws_size,
                              hipStream_t stream) {
    const float* xp    = (const float*)d_in[0];
    const float* Ww    = (const float*)d_in[1];
    const float* bw    = (const float*)d_in[2];
    const float* cross = (const float*)d_in[3];
    const float* W1    = (const float*)d_in[4];
    const float* b1    = (const float*)d_in[5];
    const float* w2    = (const float*)d_in[6];
    const float* Wd1   = (const float*)d_in[7];
    const float* bd1   = (const float*)d_in[8];
    const float* Wd2   = (const float*)d_in[9];
    const float* bd2   = (const float*)d_in[10];
    const float* Wd3   = (const float*)d_in[11];
    const float* bd3   = (const float*)d_in[12];
    const float* Wo    = (const float*)d_in[13];
    const float* bo    = (const float*)d_in[14];
    float* outp = (float*)d_out;

    afm_r6_kernel<<<BB, THREADS, 0, stream>>>(xp, Ww, bw, cross, W1, b1, w2,
                                              Wd1, bd1, Wd2, bd2, Wd3, bd3,
                                              Wo, bo, outp);
}